// Round 1
// baseline (302.515 us; speedup 1.0000x reference)
//
#include <hip/hip_runtime.h>
#include <stdint.h>

#define NN 10000
#define NE 320000
#define DF 128
#define OD 128
#define NS 3

typedef __attribute__((ext_vector_type(8))) short bf16x8;
typedef __attribute__((ext_vector_type(16))) float f32x16;

static __device__ __forceinline__ uint32_t f2bf(float f) {
  uint32_t u = __float_as_uint(f);
  return (u + 0x7FFFu + ((u >> 16) & 1u)) >> 16;
}
static __device__ __forceinline__ float bflo(uint32_t u) { return __uint_as_float(u << 16); }
static __device__ __forceinline__ float bfhi(uint32_t u) { return __uint_as_float(u & 0xFFFF0000u); }

static __device__ __forceinline__ uint32_t relu2(uint32_t a, uint32_t d) {
  float f0 = fmaxf(bflo(a) + bflo(d), 0.0f);
  float f1 = fmaxf(bfhi(a) + bfhi(d), 0.0f);
  return f2bf(f0) | (f2bf(f1) << 16);
}

// ---------------------------------------------------------------------------
// Kernel 0: W2 [3][128][128] fp32 -> W2T [s][n][k] bf16, and bmean = mean_s b2
// ---------------------------------------------------------------------------
__global__ __launch_bounds__(256) void prep_w2(
    const float* __restrict__ W2, const float* __restrict__ b2,
    unsigned short* __restrict__ w2t, float* __restrict__ bmean)
{
  int tid = blockIdx.x * 256 + threadIdx.x;         // 192 blocks -> 49152
  if (tid < NS * OD * OD) {
    int s = tid / (OD * OD);
    int r = tid % (OD * OD);
    int k = r / OD;          // W2 row (h index)
    int n = r % OD;          // W2 col (output index) -- coalesced read
    w2t[(s * OD + n) * OD + k] = (unsigned short)f2bf(W2[tid]);
  }
  if (tid < OD) bmean[tid] = (b2[tid] + b2[OD + tid] + b2[2 * OD + tid]) * (1.0f / 3.0f);
}

// ---------------------------------------------------------------------------
// Kernel 1: per-node projections (layer-1 hoist), MFMA 32x32x16 bf16.
//   Qsrc[node][s][o] = nf[node] @ W1[s][0:128]   + b1[s] + t[node]*W1[s][256]
//   Qdst[node][s][o] = nf[node] @ W1[s][128:256]         - t[node]*W1[s][256]
// grid = (313 node-tiles, 6 chunks=(scale,proj)), block = 256
// ---------------------------------------------------------------------------
__global__ __launch_bounds__(256) void node_proj(
    const float* __restrict__ nf, const float* __restrict__ temporal,
    const float* __restrict__ W1, const float* __restrict__ b1,
    unsigned short* __restrict__ Qsrc, unsigned short* __restrict__ Qdst)
{
  __shared__ unsigned short Asm[8 * 64 * 8];       // A frags: (q, lane) x 8 ushort = 8 KB
  __shared__ unsigned short Bsm[4 * 8 * 64 * 8];   // B frags: (ntile, q, lane) = 32 KB
  __shared__ float tsh[32];

  const int t = threadIdx.x;
  const int m0 = blockIdx.x * 32;
  const int c = blockIdx.y;
  const int s = c >> 1, proj = c & 1;

  if (t < 32) {
    int node = m0 + t;
    tsh[t] = (node < NN) ? temporal[node] : 0.0f;
  }

  // stage A: nf rows -> bf16 fragment layout
  {
    int m = t >> 3, j16 = t & 7;
    int node = m0 + m;
    float v[16];
    if (node < NN) {
      const float4* p = (const float4*)(nf + (size_t)node * DF + j16 * 16);
      #pragma unroll
      for (int i = 0; i < 4; i++) {
        float4 x = p[i];
        v[4 * i] = x.x; v[4 * i + 1] = x.y; v[4 * i + 2] = x.z; v[4 * i + 3] = x.w;
      }
    } else {
      #pragma unroll
      for (int i = 0; i < 16; i++) v[i] = 0.0f;
    }
    uint32_t pk[8];
    #pragma unroll
    for (int i = 0; i < 8; i++) pk[i] = f2bf(v[2 * i]) | (f2bf(v[2 * i + 1]) << 16);
    uint32_t* d0 = (uint32_t*)(Asm + (j16 * 64 + m) * 8);
    uint32_t* d1 = (uint32_t*)(Asm + (j16 * 64 + 32 + m) * 8);
    d0[0] = pk[0]; d0[1] = pk[1]; d0[2] = pk[2]; d0[3] = pk[3];
    d1[0] = pk[4]; d1[1] = pk[5]; d1[2] = pk[6]; d1[3] = pk[7];
  }

  // stage B: W1 slice (128k x 128o) transposed -> bf16 fragment layout
  {
    int o = t & 127, qh = t >> 7;                  // qh in 0..1
    const float* wbase = W1 + (size_t)(s * 257 + proj * 128) * OD + o;
    int nt = o >> 5, lnlo = o & 31;
    #pragma unroll
    for (int r = 0; r < 8; r++) {
      int kh = qh * 8 + r;                          // 0..15
      float v[8];
      #pragma unroll
      for (int j = 0; j < 8; j++) v[j] = wbase[(size_t)(kh * 8 + j) * OD];
      uint32_t pk[4];
      #pragma unroll
      for (int i = 0; i < 4; i++) pk[i] = f2bf(v[2 * i]) | (f2bf(v[2 * i + 1]) << 16);
      int q = kh >> 1, half = kh & 1;
      uint32_t* d = (uint32_t*)(Bsm + ((nt * 8 + q) * 64 + half * 32 + lnlo) * 8);
      d[0] = pk[0]; d[1] = pk[1]; d[2] = pk[2]; d[3] = pk[3];
    }
  }
  __syncthreads();

  const int lane = t & 63, w = t >> 6;
  f32x16 C;
  #pragma unroll
  for (int i = 0; i < 16; i++) C[i] = 0.0f;
  #pragma unroll
  for (int q = 0; q < 8; q++) {
    bf16x8 a = *(const bf16x8*)(Asm + (q * 64 + lane) * 8);
    bf16x8 b = *(const bf16x8*)(Bsm + ((w * 8 + q) * 64 + lane) * 8);
    C = __builtin_amdgcn_mfma_f32_32x32x16_bf16(a, b, C, 0, 0, 0);
  }

  const int o = w * 32 + (lane & 31);
  const float w1gv = W1[(size_t)(s * 257 + 256) * OD + o];
  const float b1v = b1[s * OD + o];
  unsigned short* Qt = (proj == 0) ? Qsrc : Qdst;
  #pragma unroll
  for (int r = 0; r < 16; r++) {
    int row = (r & 3) + 8 * (r >> 2) + 4 * (lane >> 5);
    int node = m0 + row;
    if (node < NN) {
      float val = C[r];
      if (proj == 0) val += b1v + tsh[row] * w1gv;
      else           val -= tsh[row] * w1gv;
      Qt[(size_t)node * (NS * OD) + s * OD + o] = (unsigned short)f2bf(val);
    }
  }
}

// ---------------------------------------------------------------------------
// Kernel 2: edge kernel. 128 edges/block (4 tiles of 32).
//   h[s] = relu(Qsrc[src] + Qdst[dst]); out = (sum_s h[s] @ W2[s]) / 3 + bmean
// Each wave owns a 32-wide n-tile, holds all 24 W2 B-frags in registers,
// accumulates all 3 scales into one C. h goes through LDS in fragment layout.
// ---------------------------------------------------------------------------
__global__ __launch_bounds__(256) void edge_mlp(
    const unsigned short* __restrict__ Qsrc, const unsigned short* __restrict__ Qdst,
    const unsigned short* __restrict__ W2T, const float* __restrict__ bmean,
    const int* __restrict__ ei, float* __restrict__ out)
{
  __shared__ unsigned short hsm[NS * 8 * 64 * 8];   // 24 KB, frag layout (s,q,lane)

  const int t = threadIdx.x;
  const int lane = t & 63, w = t >> 6;
  const int nlo = lane & 31, khi = lane >> 5;

  // persistent B fragments: W2T[s][n][k], k contiguous
  bf16x8 bfrag[NS][8];
  {
    int n = w * 32 + nlo;
    #pragma unroll
    for (int s = 0; s < NS; s++) {
      const unsigned short* base = W2T + ((s * OD + n) * OD + khi * 8);
      #pragma unroll
      for (int q = 0; q < 8; q++)
        bfrag[s][q] = *(const bf16x8*)(base + q * 16);
    }
  }
  const float bmv = bmean[w * 32 + nlo];

  const int m = t >> 3, j16 = t & 7;   // producer mapping: 8 lanes/edge -> coalesced rows

  for (int tt = 0; tt < 4; tt++) {
    const int e0 = blockIdx.x * 128 + tt * 32;
    // ---- producer: h = relu(Qsrc[src] + Qdst[dst]) -> LDS frag layout ----
    {
      const int e = e0 + m;
      const int srcn = ei[e];
      const int dstn = ei[NE + e];
      const unsigned short* ps = Qsrc + (size_t)srcn * (NS * OD) + j16 * 16;
      const unsigned short* pd = Qdst + (size_t)dstn * (NS * OD) + j16 * 16;
      #pragma unroll
      for (int s = 0; s < NS; s++) {
        uint4 a0 = *(const uint4*)(ps + s * OD);
        uint4 a1 = *(const uint4*)(ps + s * OD + 8);
        uint4 d0 = *(const uint4*)(pd + s * OD);
        uint4 d1 = *(const uint4*)(pd + s * OD + 8);
        uint4 w0, w1;
        w0.x = relu2(a0.x, d0.x); w0.y = relu2(a0.y, d0.y);
        w0.z = relu2(a0.z, d0.z); w0.w = relu2(a0.w, d0.w);
        w1.x = relu2(a1.x, d1.x); w1.y = relu2(a1.y, d1.y);
        w1.z = relu2(a1.z, d1.z); w1.w = relu2(a1.w, d1.w);
        *(uint4*)(hsm + ((s * 8 + j16) * 64 + m) * 8) = w0;       // k = 16*j16 + 0..7
        *(uint4*)(hsm + ((s * 8 + j16) * 64 + 32 + m) * 8) = w1;  // k = 16*j16 + 8..15
      }
    }
    __syncthreads();

    // ---- consumer: C = sum_s h_s @ W2_s ----
    f32x16 C;
    #pragma unroll
    for (int i = 0; i < 16; i++) C[i] = 0.0f;
    #pragma unroll
    for (int s = 0; s < NS; s++) {
      #pragma unroll
      for (int q = 0; q < 8; q++) {
        bf16x8 a = *(const bf16x8*)(hsm + ((s * 8 + q) * 64 + lane) * 8);
        C = __builtin_amdgcn_mfma_f32_32x32x16_bf16(a, bfrag[s][q], C, 0, 0, 0);
      }
    }

    // ---- epilogue: out = C/3 + bmean ----
    #pragma unroll
    for (int r = 0; r < 16; r++) {
      int row = (r & 3) + 8 * (r >> 2) + 4 * khi;
      out[(size_t)(e0 + row) * OD + w * 32 + nlo] = C[r] * (1.0f / 3.0f) + bmv;
    }
    __syncthreads();
  }
}

extern "C" void kernel_launch(void* const* d_in, const int* in_sizes, int n_in,
                              void* d_out, int out_size, void* d_ws, size_t ws_size,
                              hipStream_t stream) {
  const float* nf       = (const float*)d_in[0];
  const float* temporal = (const float*)d_in[1];
  const float* W1       = (const float*)d_in[2];
  const float* b1       = (const float*)d_in[3];
  const float* W2       = (const float*)d_in[4];
  const float* b2       = (const float*)d_in[5];
  const int*   ei       = (const int*)d_in[6];
  float* out = (float*)d_out;

  char* ws = (char*)d_ws;
  unsigned short* Qsrc = (unsigned short*)ws;                       // 10000*384*2 = 7,680,000 B
  unsigned short* Qdst = (unsigned short*)(ws + 7680000);           // 7,680,000 B
  unsigned short* W2T  = (unsigned short*)(ws + 15360000);          // 98,304 B
  float*          bmv  = (float*)(ws + 15360000 + 98304);           // 512 B

  prep_w2 <<<dim3(192),     dim3(256), 0, stream>>>(W2, b2, W2T, bmv);
  node_proj<<<dim3(313, 6), dim3(256), 0, stream>>>(nf, temporal, W1, b1, Qsrc, Qdst);
  edge_mlp <<<dim3(2500),   dim3(256), 0, stream>>>(Qsrc, Qdst, W2T, bmv, ei, out);
}

// Round 2
// 266.830 us; speedup vs baseline: 1.1337x; 1.1337x over previous
//
#include <hip/hip_runtime.h>
#include <stdint.h>

#define NN 10000
#define NE 320000
#define DF 128
#define OD 128
#define NS 3

typedef __attribute__((ext_vector_type(8))) short bf16x8;
typedef __attribute__((ext_vector_type(16))) float f32x16;

static __device__ __forceinline__ uint32_t f2bf(float f) {
  uint32_t u = __float_as_uint(f);
  return (u + 0x7FFFu + ((u >> 16) & 1u)) >> 16;
}
static __device__ __forceinline__ float bflo(uint32_t u) { return __uint_as_float(u << 16); }
static __device__ __forceinline__ float bfhi(uint32_t u) { return __uint_as_float(u & 0xFFFF0000u); }

static __device__ __forceinline__ uint32_t relu2(uint32_t a, uint32_t d) {
  float f0 = fmaxf(bflo(a) + bflo(d), 0.0f);
  float f1 = fmaxf(bfhi(a) + bfhi(d), 0.0f);
  return f2bf(f0) | (f2bf(f1) << 16);
}

// ---------------------------------------------------------------------------
// Kernel 0: W2 [3][128][128] fp32 -> W2T [s][n][k] bf16, and bmean = mean_s b2
// ---------------------------------------------------------------------------
__global__ __launch_bounds__(256) void prep_w2(
    const float* __restrict__ W2, const float* __restrict__ b2,
    unsigned short* __restrict__ w2t, float* __restrict__ bmean)
{
  int tid = blockIdx.x * 256 + threadIdx.x;
  if (tid < NS * OD * OD) {
    int s = tid / (OD * OD);
    int r = tid % (OD * OD);
    int k = r / OD;
    int n = r % OD;
    w2t[(s * OD + n) * OD + k] = (unsigned short)f2bf(W2[tid]);
  }
  if (tid < OD) bmean[tid] = (b2[tid] + b2[OD + tid] + b2[2 * OD + tid]) * (1.0f / 3.0f);
}

// ---------------------------------------------------------------------------
// Kernel 1: per-node projections (layer-1 hoist), MFMA 32x32x16 bf16.
//   Qsrc[node][s][o] = nf[node] @ W1[s][0:128]   + b1[s] + t[node]*W1[s][256]
//   Qdst[node][s][o] = nf[node] @ W1[s][128:256]         - t[node]*W1[s][256]
// grid = (40 blocks x 8 node-tiles, 6 chunks=(scale,proj)); W1 slice staged
// to LDS ONCE per block (amortized over 8 tiles). Asm is XOR-swizzled.
// ---------------------------------------------------------------------------
__global__ __launch_bounds__(256) void node_proj(
    const float* __restrict__ nf, const float* __restrict__ temporal,
    const float* __restrict__ W1, const float* __restrict__ b1,
    unsigned short* __restrict__ Qsrc, unsigned short* __restrict__ Qdst)
{
  __shared__ unsigned short Asm[8 * 64 * 8];       // 8 KB, swizzled frag layout
  __shared__ unsigned short Bsm[4 * 8 * 64 * 8];   // 32 KB
  __shared__ float tsh[32];

  const int t = threadIdx.x;
  const int c = blockIdx.y;
  const int s = c >> 1, proj = c & 1;

  // ---- stage B once: W1 slice (128k x 128o) -> bf16 fragment layout ----
  {
    int o = t & 127, qh = t >> 7;
    const float* wbase = W1 + (size_t)(s * 257 + proj * 128) * OD + o;
    int nt = o >> 5, lnlo = o & 31;
    #pragma unroll
    for (int r = 0; r < 8; r++) {
      int kh = qh * 8 + r;
      float v[8];
      #pragma unroll
      for (int j = 0; j < 8; j++) v[j] = wbase[(size_t)(kh * 8 + j) * OD];
      uint32_t pk[4];
      #pragma unroll
      for (int i = 0; i < 4; i++) pk[i] = f2bf(v[2 * i]) | (f2bf(v[2 * i + 1]) << 16);
      int q = kh >> 1, half = kh & 1;
      uint32_t* d = (uint32_t*)(Bsm + ((nt * 8 + q) * 64 + half * 32 + lnlo) * 8);
      d[0] = pk[0]; d[1] = pk[1]; d[2] = pk[2]; d[3] = pk[3];
    }
  }

  const int lane = t & 63, w = t >> 6;
  const int o = w * 32 + (lane & 31);
  const float w1gv = W1[(size_t)(s * 257 + 256) * OD + o];
  const float b1v = b1[s * OD + o];
  unsigned short* Qt = (proj == 0) ? Qsrc : Qdst;
  const int m = t >> 3, j16 = t & 7;

  for (int it = 0; it < 8; it++) {
    const int m0 = (blockIdx.x * 8 + it) * 32;
    if (m0 >= NN) break;                            // block-uniform

    if (t < 32) tsh[t] = (m0 + t < NN) ? temporal[m0 + t] : 0.0f;

    // ---- stage A: nf rows -> swizzled bf16 fragment layout ----
    {
      int node = m0 + m;
      float v[16];
      if (node < NN) {
        const float4* p = (const float4*)(nf + (size_t)node * DF + j16 * 16);
        #pragma unroll
        for (int i = 0; i < 4; i++) {
          float4 x = p[i];
          v[4 * i] = x.x; v[4 * i + 1] = x.y; v[4 * i + 2] = x.z; v[4 * i + 3] = x.w;
        }
      } else {
        #pragma unroll
        for (int i = 0; i < 16; i++) v[i] = 0.0f;
      }
      uint32_t pk[8];
      #pragma unroll
      for (int i = 0; i < 8; i++) pk[i] = f2bf(v[2 * i]) | (f2bf(v[2 * i + 1]) << 16);
      uint32_t* d0 = (uint32_t*)(Asm + (j16 * 64 + (m ^ j16)) * 8);
      uint32_t* d1 = (uint32_t*)(Asm + (j16 * 64 + ((32 + m) ^ j16)) * 8);
      d0[0] = pk[0]; d0[1] = pk[1]; d0[2] = pk[2]; d0[3] = pk[3];
      d1[0] = pk[4]; d1[1] = pk[5]; d1[2] = pk[6]; d1[3] = pk[7];
    }
    __syncthreads();

    f32x16 C;
    #pragma unroll
    for (int i = 0; i < 16; i++) C[i] = 0.0f;
    #pragma unroll
    for (int q = 0; q < 8; q++) {
      bf16x8 a = *(const bf16x8*)(Asm + (q * 64 + (lane ^ q)) * 8);
      bf16x8 b = *(const bf16x8*)(Bsm + ((w * 8 + q) * 64 + lane) * 8);
      C = __builtin_amdgcn_mfma_f32_32x32x16_bf16(a, b, C, 0, 0, 0);
    }

    #pragma unroll
    for (int r = 0; r < 16; r++) {
      int row = (r & 3) + 8 * (r >> 2) + 4 * (lane >> 5);
      int node = m0 + row;
      if (node < NN) {
        float val = C[r];
        if (proj == 0) val += b1v + tsh[row] * w1gv;
        else           val -= tsh[row] * w1gv;
        Qt[(size_t)node * (NS * OD) + s * OD + o] = (unsigned short)f2bf(val);
      }
    }
    __syncthreads();
  }
}

// ---------------------------------------------------------------------------
// Kernel 2: edge kernel. 128 edges/block (4 tiles of 32).
//   h[s] = relu(Qsrc[src] + Qdst[dst]); out = (sum_s h[s] @ W2[s]) / 3 + bmean
// XOR-swizzled h layout in LDS (kills 8-way producer write conflicts), and
// register prefetch of tile tt+1's gathers during tile tt's MFMA phase.
// ---------------------------------------------------------------------------
__global__ __launch_bounds__(256) void edge_mlp(
    const unsigned short* __restrict__ Qsrc, const unsigned short* __restrict__ Qdst,
    const unsigned short* __restrict__ W2T, const float* __restrict__ bmean,
    const int* __restrict__ ei, float* __restrict__ out)
{
  __shared__ unsigned short hsm[NS * 8 * 64 * 8];   // 24 KB, swizzled frag layout

  const int t = threadIdx.x;
  const int lane = t & 63, w = t >> 6;
  const int nlo = lane & 31, khi = lane >> 5;

  // persistent B fragments: W2T[s][n][k], k contiguous (lands in AGPRs)
  bf16x8 bfrag[NS][8];
  {
    int n = w * 32 + nlo;
    #pragma unroll
    for (int s = 0; s < NS; s++) {
      const unsigned short* base = W2T + ((s * OD + n) * OD + khi * 8);
      #pragma unroll
      for (int q = 0; q < 8; q++)
        bfrag[s][q] = *(const bf16x8*)(base + q * 16);
    }
  }
  const float bmv = bmean[w * 32 + nlo];

  const int m = t >> 3, j16 = t & 7;   // producer mapping: 8 lanes/edge

  // all 4 tiles' edge indices up front
  int sn[4], dn[4];
  #pragma unroll
  for (int tt = 0; tt < 4; tt++) {
    int e = blockIdx.x * 128 + tt * 32 + m;
    sn[tt] = ei[e];
    dn[tt] = ei[NE + e];
  }

  uint4 G[12], G2[12];
  // prefetch tile 0
  {
    const unsigned short* ps = Qsrc + (size_t)sn[0] * (NS * OD) + j16 * 16;
    const unsigned short* pd = Qdst + (size_t)dn[0] * (NS * OD) + j16 * 16;
    #pragma unroll
    for (int s = 0; s < NS; s++) {
      G[4 * s + 0] = *(const uint4*)(ps + s * OD);
      G[4 * s + 1] = *(const uint4*)(ps + s * OD + 8);
      G[4 * s + 2] = *(const uint4*)(pd + s * OD);
      G[4 * s + 3] = *(const uint4*)(pd + s * OD + 8);
    }
  }

  #pragma unroll
  for (int tt = 0; tt < 4; tt++) {
    const int e0 = blockIdx.x * 128 + tt * 32;

    // ---- producer: h = relu(src + dst) -> LDS (swizzled frag layout) ----
    #pragma unroll
    for (int s = 0; s < NS; s++) {
      uint4 a0 = G[4 * s + 0], a1 = G[4 * s + 1];
      uint4 d0 = G[4 * s + 2], d1 = G[4 * s + 3];
      uint4 w0, w1;
      w0.x = relu2(a0.x, d0.x); w0.y = relu2(a0.y, d0.y);
      w0.z = relu2(a0.z, d0.z); w0.w = relu2(a0.w, d0.w);
      w1.x = relu2(a1.x, d1.x); w1.y = relu2(a1.y, d1.y);
      w1.z = relu2(a1.z, d1.z); w1.w = relu2(a1.w, d1.w);
      // row = s*8 + j16 ; logical pos m and 32+m ; physical pos = pos ^ j16
      *(uint4*)(hsm + ((s * 8 + j16) * 64 + (m ^ j16)) * 8) = w0;
      *(uint4*)(hsm + ((s * 8 + j16) * 64 + ((32 + m) ^ j16)) * 8) = w1;
    }

    // ---- prefetch tile tt+1 into G2 (in flight across the MFMA phase) ----
    if (tt < 3) {
      const unsigned short* ps = Qsrc + (size_t)sn[tt + 1] * (NS * OD) + j16 * 16;
      const unsigned short* pd = Qdst + (size_t)dn[tt + 1] * (NS * OD) + j16 * 16;
      #pragma unroll
      for (int s = 0; s < NS; s++) {
        G2[4 * s + 0] = *(const uint4*)(ps + s * OD);
        G2[4 * s + 1] = *(const uint4*)(ps + s * OD + 8);
        G2[4 * s + 2] = *(const uint4*)(pd + s * OD);
        G2[4 * s + 3] = *(const uint4*)(pd + s * OD + 8);
      }
    }
    __syncthreads();

    // ---- consumer: C = sum_s h_s @ W2_s ----
    f32x16 C;
    #pragma unroll
    for (int i = 0; i < 16; i++) C[i] = 0.0f;
    #pragma unroll
    for (int s = 0; s < NS; s++) {
      #pragma unroll
      for (int q = 0; q < 8; q++) {
        bf16x8 a = *(const bf16x8*)(hsm + ((s * 8 + q) * 64 + (lane ^ q)) * 8);
        C = __builtin_amdgcn_mfma_f32_32x32x16_bf16(a, bfrag[s][q], C, 0, 0, 0);
      }
    }

    // ---- epilogue: out = C/3 + bmean ----
    #pragma unroll
    for (int r = 0; r < 16; r++) {
      int row = (r & 3) + 8 * (r >> 2) + 4 * khi;
      out[(size_t)(e0 + row) * OD + w * 32 + nlo] = C[r] * (1.0f / 3.0f) + bmv;
    }
    __syncthreads();

    #pragma unroll
    for (int i = 0; i < 12; i++) G[i] = G2[i];
  }
}

extern "C" void kernel_launch(void* const* d_in, const int* in_sizes, int n_in,
                              void* d_out, int out_size, void* d_ws, size_t ws_size,
                              hipStream_t stream) {
  const float* nf       = (const float*)d_in[0];
  const float* temporal = (const float*)d_in[1];
  const float* W1       = (const float*)d_in[2];
  const float* b1       = (const float*)d_in[3];
  const float* W2       = (const float*)d_in[4];
  const float* b2       = (const float*)d_in[5];
  const int*   ei       = (const int*)d_in[6];
  float* out = (float*)d_out;

  char* ws = (char*)d_ws;
  unsigned short* Qsrc = (unsigned short*)ws;                       // 7,680,000 B
  unsigned short* Qdst = (unsigned short*)(ws + 7680000);           // 7,680,000 B
  unsigned short* W2T  = (unsigned short*)(ws + 15360000);          // 98,304 B
  float*          bmv  = (float*)(ws + 15360000 + 98304);           // 512 B

  prep_w2 <<<dim3(192),    dim3(256), 0, stream>>>(W2, b2, W2T, bmv);
  node_proj<<<dim3(40, 6), dim3(256), 0, stream>>>(nf, temporal, W1, b1, Qsrc, Qdst);
  edge_mlp <<<dim3(2500),  dim3(256), 0, stream>>>(Qsrc, Qdst, W2T, bmv, ei, out);
}